// Round 1
// baseline (233.219 us; speedup 1.0000x reference)
//
#include <hip/hip_runtime.h>

typedef unsigned short u16;
typedef __attribute__((ext_vector_type(8))) short bf16x8;
typedef __attribute__((ext_vector_type(4))) float f32x4;

constexpr int SZb   = 4096;
constexpr int SEN   = 128;
constexpr int DWE   = 100;
constexpr int DC    = 128;
constexpr int CIN   = 270;   // 100 + 2*5 + 32 + 8*16
constexpr int CPAD  = 288;   // padded channel count (multiple of 32)
constexpr int KP    = 3 * CPAD;  // 864, GEMM K
constexpr int PITCH = 296;   // xT row pitch in bf16 (592B rows -> conflict-free b128)
constexpr int ROWS  = 130;   // 128 positions + 2 zero pad rows
constexpr int NOUT  = 984;   // 3*128 + 6*100

__device__ inline u16 f2bf(float f) {
    unsigned u = __float_as_uint(f);
    return (u16)((u + 0x7FFFu + ((u >> 16) & 1u)) >> 16);
}

// ---------------------------------------------------------------------------
// Repack conv_w [DC][CIN][3] fp32 -> A' [DC][KP] bf16, K = k*CPAD + c
// ---------------------------------------------------------------------------
__global__ void prep_w(const float* __restrict__ w, u16* __restrict__ Ap) {
    int i = blockIdx.x * 256 + threadIdx.x;
    if (i >= DC * KP) return;
    int dc = i / KP;
    int K  = i - dc * KP;
    int k  = K / CPAD;
    int c  = K - k * CPAD;
    float v = (c < CIN) ? w[(dc * CIN + c) * 3 + k] : 0.0f;
    Ap[i] = f2bf(v);
}

// ---------------------------------------------------------------------------
// loc path: out[s][384..983] (pure fp32)
// ---------------------------------------------------------------------------
__global__ void loc_kern(const int* __restrict__ loc, const int* __restrict__ lmark,
                         const float* __restrict__ we, float* __restrict__ out) {
    int s = blockIdx.x;
    int d = threadIdx.x;
    if (d >= DWE) return;
    const int* L = loc + s * 16;
    float* o = out + (size_t)s * NOUT + 384;
#pragma unroll
    for (int i = 0; i < 4; i++)
        o[i * DWE + d] = tanhf(we[(size_t)L[i] * DWE + d]);
    int mk = lmark[s];  // 1..11
    float acc = 0.0f;
    for (int j = 0; j < mk; j++)
        acc += we[(size_t)L[4 + j] * DWE + d];
    o[4 * DWE + d] = tanhf(acc / (float)mk);
    o[5 * DWE + d] = tanhf(we[(size_t)L[4 + mk] * DWE + d]);
}

// ---------------------------------------------------------------------------
// Main: per-sample im2col-free conv GEMM + masked max pool + tanh
// block = 256 threads (4 waves in 2x2 grid of 64x64 output tiles)
// ---------------------------------------------------------------------------
struct alignas(8) U16x4 { u16 a, b, c, d; };

__global__ __launch_bounds__(256, 2)
void conv_pool(const int* __restrict__ inp, const int* __restrict__ pos1,
               const int* __restrict__ pos2, const int* __restrict__ subtype,
               const int* __restrict__ argRole,
               const float* __restrict__ maskL, const float* __restrict__ maskM,
               const float* __restrict__ maskR,
               const float* __restrict__ we, const float* __restrict__ pe,
               const float* __restrict__ ee, const float* __restrict__ re,
               const u16* __restrict__ Ap, const float* __restrict__ cb,
               float* __restrict__ out)
{
    __shared__ __align__(16) u16 xT[ROWS * PITCH];   // 76,960 B; reused as C fp32 later
    __shared__ float msk[3 * SEN];
    __shared__ __align__(16) u16 cvec[160];          // event(32) + roles(128), bf16

    const int s   = blockIdx.x;
    const int tid = threadIdx.x;

    // --- phase 0: zero xT (rows 0,129 and cols>=270 must be exactly 0) ---
    {
        int4 z = {0, 0, 0, 0};
        int4* p = (int4*)xT;
        const int n16 = ROWS * PITCH * 2 / 16;  // 4810
        for (int i = tid; i < n16; i += 256) p[i] = z;
    }
    // masks -> LDS fp32
    if (tid < SEN) {
        msk[tid]           = maskL[(size_t)s * SEN + tid];
        msk[SEN + tid]     = maskM[(size_t)s * SEN + tid];
        msk[2 * SEN + tid] = maskR[(size_t)s * SEN + tid];
    }
    // position-invariant channels (event + role embeddings) -> cvec
    if (tid < 160) {
        float v;
        if (tid < 32) {
            v = ee[subtype[s] * 32 + tid];
        } else {
            int j = (tid - 32) >> 4, d = (tid - 32) & 15;
            v = re[argRole[s * 8 + j] * 16 + d];
        }
        cvec[tid] = f2bf(v);
    }
    __syncthreads();

    // --- phase 1: fill xT rows 1..128 ---
    if (tid < SEN) {
        // word embedding row for token t (100 fp32 -> 100 bf16)
        const int t = tid;
        const size_t idx = (size_t)inp[(size_t)s * SEN + t];
        const float4* src = (const float4*)(we + idx * DWE);
        u16* dst = xT + (t + 1) * PITCH;
#pragma unroll
        for (int i = 0; i < 25; i++) {
            float4 v = src[i];
            U16x4 w4 = { f2bf(v.x), f2bf(v.y), f2bf(v.z), f2bf(v.w) };
            *(U16x4*)(dst + 4 * i) = w4;
        }
    } else {
        const int t = tid - SEN;
        u16* row = xT + (t + 1) * PITCH;
        const float* p1 = pe + pos1[(size_t)s * SEN + t] * 5;
        const float* p2 = pe + pos2[(size_t)s * SEN + t] * 5;
#pragma unroll
        for (int i = 0; i < 5; i++) {
            row[100 + i] = f2bf(p1[i]);
            row[105 + i] = f2bf(p2[i]);
        }
        // broadcast const channels into cols 110..269
        const unsigned* cv = (const unsigned*)cvec;
        unsigned* d = (unsigned*)(row + 110);  // byte offset 220: 4-aligned
#pragma unroll
        for (int i = 0; i < 80; i++) d[i] = cv[i];
    }
    __syncthreads();

    // --- phase 2: GEMM  C[dc][t] = sum_K A'[dc][K] * xT[t + k(K)][c(K)] ---
    const int lane = tid & 63;
    const int wave = tid >> 6;
    const int wm = wave >> 1, wn = wave & 1;
    const int cl = lane & 15, rg = lane >> 4;

    f32x4 acc[4][4];
#pragma unroll
    for (int i = 0; i < 4; i++)
#pragma unroll
        for (int j = 0; j < 4; j++) acc[i][j] = (f32x4){0.f, 0.f, 0.f, 0.f};

    const u16* Abase = Ap + (size_t)(wm * 64 + cl) * KP + rg * 8;
    const int tcol = wn * 64 + cl;

    for (int ks = 0; ks < KP / 32; ks++) {   // 27 steps
        const int K = ks * 32 + rg * 8;
        const int k = (K >= 2 * CPAD) ? 2 : (K >= CPAD ? 1 : 0);
        const int c = K - k * CPAD;
        bf16x8 a[4], b[4];
#pragma unroll
        for (int mf = 0; mf < 4; mf++)
            a[mf] = *(const bf16x8*)(Abase + mf * 16 * KP + ks * 32);
#pragma unroll
        for (int nf = 0; nf < 4; nf++)
            b[nf] = *(const bf16x8*)(xT + (tcol + nf * 16 + k) * PITCH + c);
#pragma unroll
        for (int mf = 0; mf < 4; mf++)
#pragma unroll
            for (int nf = 0; nf < 4; nf++)
                acc[mf][nf] = __builtin_amdgcn_mfma_f32_16x16x32_bf16(
                    a[mf], b[nf], acc[mf][nf], 0, 0, 0);
    }

    // --- phase 3: spill C to LDS (reuse xT region), pitch 129 fp32 ---
    __syncthreads();
    float* Cl = (float*)xT;
#pragma unroll
    for (int mf = 0; mf < 4; mf++) {
        const int dcr = wm * 64 + mf * 16 + rg * 4;
#pragma unroll
        for (int nf = 0; nf < 4; nf++) {
            const int t = wn * 64 + nf * 16 + cl;
#pragma unroll
            for (int r = 0; r < 4; r++)
                Cl[(dcr + r) * 129 + t] = acc[mf][nf][r];
        }
    }
    __syncthreads();

    // --- phase 4: bias + masked max-pool (exact ref semantics) + tanh ---
    if (tid < DC) {
        const int dc = tid;
        const float bias = cb[dc];
        float mL = -1e30f, mM = -1e30f, mR = -1e30f;
        const float* Crow = Cl + dc * 129;
        for (int t = 0; t < SEN; t++) {
            float v = Crow[t] + bias;
            mL = fmaxf(mL, v * msk[t] + 1.0f);
            mM = fmaxf(mM, v * msk[SEN + t] + 1.0f);
            mR = fmaxf(mR, v * msk[2 * SEN + t] + 1.0f);
        }
        float* o = out + (size_t)s * NOUT;
        o[dc]          = tanhf(mL - 1.0f);
        o[DC + dc]     = tanhf(mM - 1.0f);
        o[2 * DC + dc] = tanhf(mR - 1.0f);
    }
}

// ---------------------------------------------------------------------------
extern "C" void kernel_launch(void* const* d_in, const int* in_sizes, int n_in,
                              void* d_out, int out_size, void* d_ws, size_t ws_size,
                              hipStream_t stream) {
    const int*   inp     = (const int*)d_in[0];
    const int*   pos1    = (const int*)d_in[1];
    const int*   pos2    = (const int*)d_in[2];
    const int*   loc     = (const int*)d_in[3];
    const int*   lmark   = (const int*)d_in[4];
    const int*   subtype = (const int*)d_in[5];
    const int*   argRole = (const int*)d_in[6];
    const float* maskL   = (const float*)d_in[7];
    const float* maskM   = (const float*)d_in[8];
    const float* maskR   = (const float*)d_in[9];
    const float* we      = (const float*)d_in[10];
    const float* pe      = (const float*)d_in[11];
    const float* ee      = (const float*)d_in[12];
    const float* re      = (const float*)d_in[13];
    const float* cw      = (const float*)d_in[14];
    const float* cb      = (const float*)d_in[15];
    float* out = (float*)d_out;
    u16* Ap = (u16*)d_ws;  // 128*864*2 = 221,184 B

    hipLaunchKernelGGL(prep_w, dim3((DC * KP + 255) / 256), dim3(256), 0, stream,
                       cw, Ap);
    hipLaunchKernelGGL(conv_pool, dim3(SZb), dim3(256), 0, stream,
                       inp, pos1, pos2, subtype, argRole, maskL, maskM, maskR,
                       we, pe, ee, re, Ap, cb, out);
    hipLaunchKernelGGL(loc_kern, dim3(SZb), dim3(128), 0, stream,
                       loc, lmark, we, out);
}

// Round 2
// 137.494 us; speedup vs baseline: 1.6962x; 1.6962x over previous
//
#include <hip/hip_runtime.h>

typedef unsigned short u16;
typedef __attribute__((ext_vector_type(8))) short bf16x8;
typedef __attribute__((ext_vector_type(4))) float f32x4;

constexpr int SEN   = 128;
constexpr int DWE   = 100;
constexpr int DC    = 128;
constexpr int CIN   = 270;
constexpr int KP    = 384;    // 3 * 128 (110 variable channels padded to 128)
constexpr int PITCH = 136;    // xT row pitch (272B rows)
constexpr int ROWS  = 130;    // 128 tokens + 2 zero pad rows
constexpr int NOUT  = 984;

__device__ inline u16 f2bf(float f) {
    unsigned u = __float_as_uint(f);
    return (u16)((u + 0x7FFFu + ((u >> 16) & 1u)) >> 16);
}

struct alignas(8) U16x4 { u16 a, b, c, d; };

// ---------------------------------------------------------------------------
// prep_all: build Av (variable-channel weights, bf16, K = k*128 + c) and the
// constant-channel contribution tables SE[k][event][dc], SR[k][slot][role][dc]
// blocks [0,192): Av  [192,252): SE  [252,732): SR
// ---------------------------------------------------------------------------
__global__ void prep_all(const float* __restrict__ w, const float* __restrict__ ee,
                         const float* __restrict__ re,
                         u16* __restrict__ Av, float* __restrict__ SE,
                         float* __restrict__ SR) {
    const int b = blockIdx.x, tid = threadIdx.x;
    if (b < 192) {                       // Av: 128*384 entries
        int i = b * 256 + tid;
        int dc = i / KP, K = i - dc * KP;
        int k = K >> 7, c = K & 127;
        float v = (c < 110) ? w[(dc * CIN + c) * 3 + k] : 0.0f;
        Av[i] = f2bf(v);
    } else if (b < 252) {                // SE: 3*40*128 entries
        int i = (b - 192) * 256 + tid;
        int dc = i & 127, rest = i >> 7;   // rest < 120
        int e = rest % 40, k = rest / 40;
        float a = 0.0f;
        for (int j = 0; j < 32; j++)
            a += w[(dc * CIN + 110 + j) * 3 + k] * ee[e * 32 + j];
        SE[(k * 40 + e) * 128 + dc] = a;
    } else {                             // SR: 3*8*40*128 entries
        int i = (b - 252) * 256 + tid;
        int dc = i & 127, rest = i >> 7;   // rest < 960
        int r = rest % 40, rest2 = rest / 40;
        int j = rest2 & 7, k = rest2 >> 3;
        float a = 0.0f;
        for (int d = 0; d < 16; d++)
            a += w[(dc * CIN + 142 + j * 16 + d) * 3 + k] * re[r * 16 + d];
        SR[((k * 8 + j) * 40 + r) * 128 + dc] = a;
    }
}

// ---------------------------------------------------------------------------
// Persistent main kernel: 512 blocks x 8 samples. Per sample:
//  stage xT (110 var channels, bf16) + const sums sc[] + loc path,
//  GEMM K=384 with A in registers, in-register masked max-pool, tanh, store.
// ---------------------------------------------------------------------------
__global__ __launch_bounds__(256, 2)
void conv_pool(const int* __restrict__ inp, const int* __restrict__ pos1,
               const int* __restrict__ pos2, const int* __restrict__ loc,
               const int* __restrict__ lmark, const int* __restrict__ subtype,
               const int* __restrict__ argRole,
               const float* __restrict__ maskL, const float* __restrict__ maskM,
               const float* __restrict__ maskR,
               const float* __restrict__ we, const float* __restrict__ pe,
               const float* __restrict__ cb,
               const u16* __restrict__ Av, const float* __restrict__ SE,
               const float* __restrict__ SR, float* __restrict__ out)
{
    __shared__ __align__(16) u16 xT[ROWS * PITCH];   // 35,360 B
    __shared__ float sc[3][DC];                      // sall, s0, s2
    __shared__ float po[3 * DC];

    const int tid  = threadIdx.x;
    const int lane = tid & 63;
    const int wv   = tid >> 6;       // wave id 0..3, owns dc [wv*32, wv*32+32)
    const int cl   = lane & 15;
    const int rg   = lane >> 4;

    // zero xT once (pad rows 0/129 and cols 110..135 stay zero forever)
    {
        int4 z = {0, 0, 0, 0};
        int4* p = (int4*)xT;
        for (int i = tid; i < ROWS * PITCH * 2 / 16; i += 256) p[i] = z;
    }

    // A slice into registers: rows wv*32 + mf*16 + cl, all K
    bf16x8 A[12][2];
#pragma unroll
    for (int ks = 0; ks < 12; ks++)
#pragma unroll
        for (int mf = 0; mf < 2; mf++)
            A[ks][mf] = *(const bf16x8*)(Av + (size_t)(wv * 32 + mf * 16 + cl) * KP
                                         + ks * 32 + rg * 8);
    __syncthreads();

    for (int it = 0; it < 8; ++it) {
        const int s = blockIdx.x * 8 + it;

        // ---- phase 1: staging ----
        if (tid < 128) {
            const int t = tid;
            const size_t idx = (size_t)inp[(size_t)s * SEN + t];
            const float4* src = (const float4*)(we + idx * DWE);
            u16* dst = xT + (t + 1) * PITCH;
#pragma unroll
            for (int i = 0; i < 12; i++) {
                float4 a0 = src[2 * i], a1 = src[2 * i + 1];
                union { bf16x8 v; u16 u[8]; } pk;
                pk.u[0] = f2bf(a0.x); pk.u[1] = f2bf(a0.y);
                pk.u[2] = f2bf(a0.z); pk.u[3] = f2bf(a0.w);
                pk.u[4] = f2bf(a1.x); pk.u[5] = f2bf(a1.y);
                pk.u[6] = f2bf(a1.z); pk.u[7] = f2bf(a1.w);
                *(bf16x8*)(dst + 8 * i) = pk.v;
            }
            { // floats 96..99
                float4 a = src[24];
                U16x4 w4 = { f2bf(a.x), f2bf(a.y), f2bf(a.z), f2bf(a.w) };
                *(U16x4*)(dst + 96) = w4;
            }
            // constant-channel sums for dc = tid
            const int sub = subtype[s];
            float sk[3];
#pragma unroll
            for (int k = 0; k < 3; k++) {
                float a = SE[(k * 40 + sub) * 128 + tid];
#pragma unroll
                for (int j = 0; j < 8; j++) {
                    int r = argRole[s * 8 + j];
                    a += SR[((k * 8 + j) * 40 + r) * 128 + tid];
                }
                sk[k] = a;
            }
            sc[0][tid] = sk[0] + sk[1] + sk[2] + cb[tid];
            sc[1][tid] = sk[0];
            sc[2][tid] = sk[2];
        } else {
            const int t = tid - 128;
            u16* row = xT + (t + 1) * PITCH + 100;
            const float* p1 = pe + pos1[(size_t)s * SEN + t] * 5;
            const float* p2 = pe + pos2[(size_t)s * SEN + t] * 5;
#pragma unroll
            for (int i = 0; i < 5; i++) {
                row[i]     = f2bf(p1[i]);
                row[5 + i] = f2bf(p2[i]);
            }
            // loc path (independent of conv), threads with t<100 -> dim d
            if (t < DWE) {
                const int d = t;
                const int* L = loc + s * 16;
                float* o = out + (size_t)s * NOUT + 384;
#pragma unroll
                for (int i = 0; i < 4; i++)
                    o[i * DWE + d] = tanhf(we[(size_t)L[i] * DWE + d]);
                const int mk = lmark[s];
                float acc = 0.0f;
                for (int j = 0; j < mk; j++)
                    acc += we[(size_t)L[4 + j] * DWE + d];
                o[4 * DWE + d] = tanhf(acc / (float)mk);
                o[5 * DWE + d] = tanhf(we[(size_t)L[4 + mk] * DWE + d]);
            }
        }
        __syncthreads();

        // ---- phase 2: GEMM, wave tile 32 dc x 128 t ----
        f32x4 acc[2][8];
#pragma unroll
        for (int mf = 0; mf < 2; mf++)
#pragma unroll
            for (int nf = 0; nf < 8; nf++)
                acc[mf][nf] = (f32x4){0.f, 0.f, 0.f, 0.f};

#pragma unroll
        for (int ks = 0; ks < 12; ks++) {
            const int k = ks >> 2;
            const int coff = (ks & 3) * 32 + rg * 8;
            bf16x8 bfr[8];
#pragma unroll
            for (int nf = 0; nf < 8; nf++)
                bfr[nf] = *(const bf16x8*)(xT + (nf * 16 + cl + k) * PITCH + coff);
#pragma unroll
            for (int mf = 0; mf < 2; mf++)
#pragma unroll
                for (int nf = 0; nf < 8; nf++)
                    acc[mf][nf] = __builtin_amdgcn_mfma_f32_16x16x32_bf16(
                        A[ks][mf], bfr[nf], acc[mf][nf], 0, 0, 0);
        }

        // ---- phase 3: in-register masked max-pool ----
        float mk0[8], mk1[8], mk2[8];
#pragma unroll
        for (int nf = 0; nf < 8; nf++) {
            const size_t mo = (size_t)s * SEN + nf * 16 + cl;
            mk0[nf] = maskL[mo]; mk1[nf] = maskM[mo]; mk2[nf] = maskR[mo];
        }
#pragma unroll
        for (int mf = 0; mf < 2; mf++) {
#pragma unroll
            for (int r = 0; r < 4; r++) {
                const int dc = wv * 32 + mf * 16 + rg * 4 + r;
                const float sall = sc[0][dc], s0c = sc[1][dc], s2c = sc[2][dc];
                float m0 = -1e30f, m1 = -1e30f, m2 = -1e30f;
#pragma unroll
                for (int nf = 0; nf < 8; nf++) {
                    float v = acc[mf][nf][r] + sall;
                    if (nf == 0) v -= (cl == 0)  ? s0c : 0.0f;   // t == 0
                    if (nf == 7) v -= (cl == 15) ? s2c : 0.0f;   // t == 127
                    m0 = fmaxf(m0, __builtin_fmaf(v, mk0[nf], 1.0f));
                    m1 = fmaxf(m1, __builtin_fmaf(v, mk1[nf], 1.0f));
                    m2 = fmaxf(m2, __builtin_fmaf(v, mk2[nf], 1.0f));
                }
#pragma unroll
                for (int d = 1; d < 16; d <<= 1) {
                    m0 = fmaxf(m0, __shfl_xor(m0, d));
                    m1 = fmaxf(m1, __shfl_xor(m1, d));
                    m2 = fmaxf(m2, __shfl_xor(m2, d));
                }
                if (cl == 0) {
                    po[0 * 128 + dc] = m0;
                    po[1 * 128 + dc] = m1;
                    po[2 * 128 + dc] = m2;
                }
            }
        }
        __syncthreads();
        {
            float* o = out + (size_t)s * NOUT;
            for (int i = tid; i < 384; i += 256)
                o[i] = tanhf(po[i] - 1.0f);
        }
        __syncthreads();   // po/sc/xT safe to overwrite next iteration
    }
}

// ---------------------------------------------------------------------------
extern "C" void kernel_launch(void* const* d_in, const int* in_sizes, int n_in,
                              void* d_out, int out_size, void* d_ws, size_t ws_size,
                              hipStream_t stream) {
    const int*   inp     = (const int*)d_in[0];
    const int*   pos1    = (const int*)d_in[1];
    const int*   pos2    = (const int*)d_in[2];
    const int*   loc     = (const int*)d_in[3];
    const int*   lmark   = (const int*)d_in[4];
    const int*   subtype = (const int*)d_in[5];
    const int*   argRole = (const int*)d_in[6];
    const float* maskL   = (const float*)d_in[7];
    const float* maskM   = (const float*)d_in[8];
    const float* maskR   = (const float*)d_in[9];
    const float* we      = (const float*)d_in[10];
    const float* pe      = (const float*)d_in[11];
    const float* cw      = (const float*)d_in[14];
    const float* cb      = (const float*)d_in[15];
    float* out = (float*)d_out;

    char* ws = (char*)d_ws;
    u16*   Av = (u16*)ws;                        // 98,304 B
    float* SE = (float*)(ws + 98304);            // 61,440 B
    float* SR = (float*)(ws + 98304 + 61440);    // 491,520 B

    hipLaunchKernelGGL(prep_all, dim3(732), dim3(256), 0, stream,
                       cw, (const float*)d_in[12], (const float*)d_in[13],
                       Av, SE, SR);
    hipLaunchKernelGGL(conv_pool, dim3(512), dim3(256), 0, stream,
                       inp, pos1, pos2, loc, lmark, subtype, argRole,
                       maskL, maskM, maskR, we, pe, cb,
                       Av, SE, SR, out);
}